// Round 5
// baseline (1030.093 us; speedup 1.0000x reference)
//
#include <hip/hip_runtime.h>
#include <math.h>

// Problem constants.
#define C_DIM 256
#define WH 12288
#define WH4 3072
#define NGROUPS 8
#define STEPS 12
#define NBLOCKS 256
#define SLOT_V4 160            // max 5 accs * 2 v4 * 16 nsub
#define SCALE 0.0625f          // 1/sqrt(256)

typedef float v4 __attribute__((ext_vector_type(4)));

__device__ __forceinline__ v4 v4max(v4 a, v4 b) {
    v4 r; r[0]=fmaxf(a[0],b[0]); r[1]=fmaxf(a[1],b[1]);
    r[2]=fmaxf(a[2],b[2]); r[3]=fmaxf(a[3],b[3]); return r;
}
__device__ __forceinline__ v4 v4exp(v4 a) {
    v4 r; r[0]=__expf(a[0]); r[1]=__expf(a[1]);
    r[2]=__expf(a[2]); r[3]=__expf(a[3]); return r;
}

// Load one item's register slab: this thread's (1 channel, 8 consecutive n,
// all L records) = up to 10 float4. Each wave instruction covers 4 channels
// x 256 B contiguous; the block's footprint per (l,c) row is 512 B.
__device__ __forceinline__ void load_slab(
    v4 (&sl)[5][2], const v4* __restrict__ x4, int item, int cl, int nsub)
{
    const int offs_[8] = {0, 5, 8, 12, 14, 19, 22, 26};
    const int lens_[8] = {5, 3, 4, 2, 5, 3, 4, 2};
    const int g = item / 384;
    const int r = item - g * 384;
    const int bn = r >> 2;
    const int chunk = r & 3;
    const int L = lens_[g];
    const size_t base = ((size_t)offs_[g] * C_DIM + chunk * 64 + cl) * WH4
                        + bn * 32 + nsub;
#pragma unroll
    for (int l = 0; l < 5; ++l) {
        if (l < L) {
#pragma unroll
            for (int j = 0; j < 2; ++j)
                sl[l][j] = __builtin_nontemporal_load(
                    &x4[base + (size_t)l * C_DIM * WH4 + 16 * j]);
        }
    }
}

// One work item: gram partial over 64 channels -> in-wave shfl (4 ch) ->
// LDS (16 waves) -> ws slot -> sibling-quad flag sync -> reduce 4 slots ->
// softmax row 0 -> context from the register slab. Prefetches the next
// item's slab before barrier1 so the sync bubble is covered by loads.
template <int L, bool ATTN>
__device__ __forceinline__ void step(
    v4 (&slab)[5][2], v4 (&slabN)[5][2],
    const v4* __restrict__ x4, v4* __restrict__ out4, v4* __restrict__ attn4,
    int* __restrict__ flags, v4* __restrict__ slots,
    v4* __restrict__ stg, v4* __restrict__ fin,
    const int s, const int b, const bool pf,
    const int wave, const int lane, const int cl, const int nsub)
{
    constexpr int NACC = ATTN ? 3 : L;   // row-0 only unless attn map (L=2)
    const int item = s * NBLOCKS + b;
    const int g = item / 384;
    const int r = item - g * 384;
    const int bn = r >> 2;
    const int chunk = r & 3;
    const int n4 = bn * 32 + nsub;

    // ---- gram partial over this thread's single channel ----
    v4 acc[NACC][2];
#pragma unroll
    for (int j = 0; j < 2; ++j) {
        if constexpr (ATTN) {
            acc[0][j] = slab[0][j] * slab[0][j];
            acc[1][j] = slab[0][j] * slab[1][j];
            acc[2][j] = slab[1][j] * slab[1][j];
        } else {
#pragma unroll
            for (int m = 0; m < L; ++m)
                acc[m][j] = slab[0][j] * slab[m][j];
        }
    }

    // ---- sum the wave's 4 channels (lane bits 4,5) ----
#pragma unroll
    for (int i = 0; i < NACC; ++i)
#pragma unroll
        for (int j = 0; j < 2; ++j) {
            v4 t;
#pragma unroll
            for (int q = 0; q < 4; ++q) t[q] = __shfl_xor(acc[i][j][q], 16);
            acc[i][j] += t;
#pragma unroll
            for (int q = 0; q < 4; ++q) t[q] = __shfl_xor(acc[i][j][q], 32);
            acc[i][j] += t;
        }

    // ---- stage per-wave partials in LDS ----
    if (lane < 16) {
#pragma unroll
        for (int i = 0; i < NACC; ++i)
#pragma unroll
            for (int j = 0; j < 2; ++j)
                stg[((wave * 5 + i) * 2 + j) * 16 + lane] = acc[i][j];
    }

    // ---- prefetch next item's slab (overlaps the whole sync phase) ----
    if (pf) load_slab(slabN, x4, item + NBLOCKS, cl, nsub);

    __syncthreads();   // barrier 1

    // ---- wave 0: block reduce -> ws slot -> quad sync -> final gram ----
    if (wave == 0) {
        const int part = lane >> 4;   // 0..3
        const int t = lane & 15;
        v4 blk[NACC][2];
#pragma unroll
        for (int i = 0; i < NACC; ++i)
#pragma unroll
            for (int j = 0; j < 2; ++j) {
                v4 a = stg[(((part * 4 + 0) * 5 + i) * 2 + j) * 16 + t];
#pragma unroll
                for (int w = 1; w < 4; ++w)
                    a += stg[(((part * 4 + w) * 5 + i) * 2 + j) * 16 + t];
                blk[i][j] = a;
            }
#pragma unroll
        for (int i = 0; i < NACC; ++i)
#pragma unroll
            for (int j = 0; j < 2; ++j) {
                v4 tv;
#pragma unroll
                for (int q = 0; q < 4; ++q) tv[q] = __shfl_xor(blk[i][j][q], 16);
                blk[i][j] += tv;
#pragma unroll
                for (int q = 0; q < 4; ++q) tv[q] = __shfl_xor(blk[i][j][q], 32);
                blk[i][j] += tv;
            }
        // store this block's 64-channel partial to its slot
        v4* slot = slots + (size_t)item * SLOT_V4;
        if (lane < 16) {
#pragma unroll
            for (int i = 0; i < NACC; ++i)
#pragma unroll
                for (int j = 0; j < 2; ++j)
                    slot[(i * 2 + j) * 16 + lane] = blk[i][j];
        }
        int* fb = flags + s * NBLOCKS + (b & ~3);
        if (lane == 0) {
            // release: waits stores + flushes to device coherence point
            __hip_atomic_store(fb + chunk, 1, __ATOMIC_RELEASE,
                               __HIP_MEMORY_SCOPE_AGENT);
            int it = 0;
            for (;;) {
                int ok = 1;
#pragma unroll
                for (int k = 0; k < 4; ++k)
                    ok &= (__hip_atomic_load(fb + k, __ATOMIC_ACQUIRE,
                                             __HIP_MEMORY_SCOPE_AGENT) == 1);
                if (ok || ++it > (1 << 24)) break;   // cap: fail visibly
                __builtin_amdgcn_s_sleep(2);
            }
        }
        // lane = t + 16*part reads sibling slot 'part'; shfl-combine the 4
        const v4* qb = slots + (size_t)(s * NBLOCKS + (b & ~3)) * SLOT_V4;
        v4 fs[NACC][2];
#pragma unroll
        for (int i = 0; i < NACC; ++i)
#pragma unroll
            for (int j = 0; j < 2; ++j)
                fs[i][j] = qb[(size_t)part * SLOT_V4 + (i * 2 + j) * 16 + t];
#pragma unroll
        for (int i = 0; i < NACC; ++i)
#pragma unroll
            for (int j = 0; j < 2; ++j) {
                v4 tv;
#pragma unroll
                for (int q = 0; q < 4; ++q) tv[q] = __shfl_xor(fs[i][j][q], 16);
                fs[i][j] += tv;
#pragma unroll
                for (int q = 0; q < 4; ++q) tv[q] = __shfl_xor(fs[i][j][q], 32);
                fs[i][j] += tv;
            }
        if (lane < 16) {
#pragma unroll
            for (int i = 0; i < NACC; ++i)
#pragma unroll
                for (int j = 0; j < 2; ++j)
                    fin[(i * 2 + j) * 16 + lane] = fs[i][j];
        }
    }
    __syncthreads();   // barrier 2

    // ---- broadcast final gram, softmax row 0, context from slab ----
    v4 sf[NACC][2];
#pragma unroll
    for (int i = 0; i < NACC; ++i)
#pragma unroll
        for (int j = 0; j < 2; ++j)
            sf[i][j] = fin[(i * 2 + j) * 16 + nsub];

    v4 p[L][2];
    v4 mx[2] = {(v4)(-INFINITY), (v4)(-INFINITY)};
#pragma unroll
    for (int m = 0; m < L; ++m)
#pragma unroll
        for (int j = 0; j < 2; ++j) {
            p[m][j] = sf[m][j] * SCALE;   // ATTN: sf[0]=s00, sf[1]=s01 = row 0
            mx[j] = v4max(mx[j], p[m][j]);
        }
    v4 sum[2] = {(v4)0.0f, (v4)0.0f};
#pragma unroll
    for (int m = 0; m < L; ++m)
#pragma unroll
        for (int j = 0; j < 2; ++j) {
            p[m][j] = v4exp(p[m][j] - mx[j]);
            sum[j] += p[m][j];
        }
    v4 inv[2];
#pragma unroll
    for (int j = 0; j < 2; ++j)
#pragma unroll
        for (int q = 0; q < 4; ++q) inv[j][q] = 1.0f / sum[j][q];

    const size_t orow = (size_t)(g * C_DIM + chunk * 64 + cl) * WH4 + n4;
#pragma unroll
    for (int j = 0; j < 2; ++j) {
        v4 o = (v4)0.0f;
#pragma unroll
        for (int m = 0; m < L; ++m) o += (p[m][j] * inv[j]) * slab[m][j];
        __builtin_nontemporal_store(o, &out4[orow + 16 * j]);
    }

    // ---- attn map rows (last group, L=2): chunk-0 blocks, threads cl<2 ----
    if constexpr (ATTN) {
        if (chunk == 0 && cl < 2) {
            const int rr = cl;   // row index
#pragma unroll
            for (int j = 0; j < 2; ++j) {
                v4 a0 = (rr == 0 ? sf[0][j] : sf[1][j]) * SCALE;
                v4 a1 = (rr == 0 ? sf[1][j] : sf[2][j]) * SCALE;
                v4 mm = v4max(a0, a1);
                v4 e0 = v4exp(a0 - mm), e1 = v4exp(a1 - mm);
                v4 iv;
#pragma unroll
                for (int q = 0; q < 4; ++q) iv[q] = 1.0f / (e0[q] + e1[q]);
                __builtin_nontemporal_store(
                    e0 * iv, &attn4[(size_t)(rr * 2 + 0) * WH4 + n4 + 16 * j]);
                __builtin_nontemporal_store(
                    e1 * iv, &attn4[(size_t)(rr * 2 + 1) * WH4 + n4 + 16 * j]);
            }
        }
    }

    // ---- rotate prefetched slab in (static indices only) ----
    if (pf) {
#pragma unroll
        for (int l = 0; l < 5; ++l)
#pragma unroll
            for (int j = 0; j < 2; ++j)
                slab[l][j] = slabN[l][j];
    }
}

// Persistent kernel: grid = 256 = #CUs, 1024 threads, VGPR<=128 -> exactly
// one block/CU resident -> all blocks co-resident -> sibling-quad spin is
// safe. 12 steps/block; items laid out ((g*96+bn)*4+chunk) so blocks
// {4q..4q+3} at the same step are siblings sharing (g, bn).
__global__ __launch_bounds__(1024, 4) void att_coop_kernel(
    const float* __restrict__ x,
    float* __restrict__ out0,
    float* __restrict__ attnp,
    int* __restrict__ ws)
{
    __shared__ v4 stg[16 * 5 * 2 * 16];   // 40 KB
    __shared__ v4 fin[5 * 2 * 16];        // 2.5 KB

    const int b = blockIdx.x;
    const int tid = threadIdx.x;
    const int wave = tid >> 6;
    const int lane = tid & 63;
    const int cl = wave * 4 + (lane >> 4);   // channel-local 0..63
    const int nsub = lane & 15;              // v4-subgroup along n

    const v4* x4 = reinterpret_cast<const v4*>(x);
    v4* out4 = reinterpret_cast<v4*>(out0);
    v4* attn4 = reinterpret_cast<v4*>(attnp);
    int* flags = ws;                                           // 12 KB, zeroed
    v4* slots = reinterpret_cast<v4*>((char*)ws + 16384);      // 7.9 MB

    v4 slab[5][2], slabN[5][2];
    load_slab(slab, x4, b, cl, nsub);

    const int lens_[8] = {5, 3, 4, 2, 5, 3, 4, 2};
    for (int s = 0; s < STEPS; ++s) {
        const int item = s * NBLOCKS + b;
        const int g = item / 384;
        const bool pf = (s + 1 < STEPS);
        switch (lens_[g]) {   // block-uniform
        case 5: step<5, false>(slab, slabN, x4, out4, attn4, flags, slots,
                               stg, fin, s, b, pf, wave, lane, cl, nsub); break;
        case 4: step<4, false>(slab, slabN, x4, out4, attn4, flags, slots,
                               stg, fin, s, b, pf, wave, lane, cl, nsub); break;
        case 3: step<3, false>(slab, slabN, x4, out4, attn4, flags, slots,
                               stg, fin, s, b, pf, wave, lane, cl, nsub); break;
        default:
            if (g == NGROUPS - 1)
                step<2, true>(slab, slabN, x4, out4, attn4, flags, slots,
                              stg, fin, s, b, pf, wave, lane, cl, nsub);
            else
                step<2, false>(slab, slabN, x4, out4, attn4, flags, slots,
                               stg, fin, s, b, pf, wave, lane, cl, nsub);
        }
    }
}

extern "C" void kernel_launch(void* const* d_in, const int* in_sizes, int n_in,
                              void* d_out, int out_size, void* d_ws, size_t ws_size,
                              hipStream_t stream) {
    const float* x = (const float*)d_in[0];
    float* out0 = (float*)d_out;                        // (8, C, W, H)
    float* attn = out0 + (size_t)NGROUPS * C_DIM * WH;  // (2, 2, W, H)
    int* ws = (int*)d_ws;                               // flags 16 KB + slots

    // Zero the sync flags each invocation (graph-capture safe, replayed).
    hipMemsetAsync(ws, 0, 16384, stream);
    att_coop_kernel<<<dim3(NBLOCKS), dim3(1024), 0, stream>>>(x, out0, attn, ws);
}